// Round 2
// baseline (444.949 us; speedup 1.0000x reference)
//
#include <hip/hip_runtime.h>

#define N_    8192
#define FIN_  256
#define NHID_ 128
#define E_    524288
#define KTOP  32
#define CAP   160   // bucket capacity per row; Binomial(E,1/N): mean 64, sigma 8 -> 160 = +12 sigma

// ---------------- GEMM: h = relu(x @ W1 + b1) ----------------
// block = 8 rows x 128 cols; thread (row = t>>5, jg = t&31) computes 4 cols.
// Per k-iter: 1 LDS broadcast read (free) + 1 float4 W1 load (L2-hit) + 4 FMA.
__global__ __launch_bounds__(256) void k_gemm(const float* __restrict__ x,
                                              const float* __restrict__ W1,
                                              const float* __restrict__ b1,
                                              float* __restrict__ h) {
    __shared__ float xs[8][FIN_];
    int t = threadIdx.x;
    int row0 = blockIdx.x * 8;
    const float4* xg = (const float4*)(x + (size_t)row0 * FIN_);
    float4* xs4 = (float4*)&xs[0][0];
    xs4[t]       = xg[t];          // 8*256 floats = 512 float4, 2 per thread
    xs4[t + 256] = xg[t + 256];
    __syncthreads();
    int row = t >> 5;
    int jg  = t & 31;
    const float* wp = W1 + jg * 4;
    float4 acc = *(const float4*)(b1 + jg * 4);
    const float* xr = xs[row];
#pragma unroll 8
    for (int k = 0; k < FIN_; ++k) {
        float4 w = *(const float4*)(wp + (size_t)k * NHID_);
        float xv = xr[k];
        acc.x += xv * w.x; acc.y += xv * w.y; acc.z += xv * w.z; acc.w += xv * w.w;
    }
    acc.x = fmaxf(acc.x, 0.f);
    acc.y = fmaxf(acc.y, 0.f);
    acc.z = fmaxf(acc.z, 0.f);
    acc.w = fmaxf(acc.w, 0.f);
    *(float4*)(h + (size_t)(row0 + row) * NHID_ + jg * 4) = acc;
}

// ---------------- per-node scalars a = h.We1, b = h.We2 ----------------
__global__ __launch_bounds__(256) void k_ab(const float* __restrict__ h,
                                            const float* __restrict__ We,
                                            float* __restrict__ a,
                                            float* __restrict__ b) {
    int t = threadIdx.x;
    int wave = t >> 6, lane = t & 63;
    int node = blockIdx.x * 4 + wave;   // one wave per node
    const float* hr = h + (size_t)node * NHID_;
    float h0 = hr[lane], h1 = hr[lane + 64];
    float p = h0 * We[lane]       + h1 * We[lane + 64];
    float q = h0 * We[128 + lane] + h1 * We[192 + lane];
    for (int o = 32; o > 0; o >>= 1) { p += __shfl_down(p, o); q += __shfl_down(q, o); }
    if (lane == 0) { a[node] = p; b[node] = q; }
}

// ---------------- bucket edges by row (fixed-capacity, atomic append) ----------------
__global__ __launch_bounds__(256) void k_scatter(const int* __restrict__ ei,
                                                 int* __restrict__ cnt,
                                                 int* __restrict__ ecol) {
    int e = blockIdx.x * 256 + threadIdx.x;
    int r = ei[e];
    int c = ei[E_ + e];
    int pos = atomicAdd(&cnt[r], 1);
    if (pos < CAP) ecol[r * CAP + pos] = c;
}

// ---------------- per-row sparsemax + topK threshold + dense row write ----------------
// Builds the full 32 KB output row in LDS, then one streaming float4 pass to HBM.
__global__ __launch_bounds__(256) void k_rows(const int* __restrict__ cnt,
                                              const int* __restrict__ ecol,
                                              const float* __restrict__ a,
                                              const float* __restrict__ b,
                                              const float* __restrict__ be,
                                              float* __restrict__ adj) {
    __shared__ float rowbuf[N_];          // 32 KB dense row
    __shared__ float zs[CAP];
    __shared__ int   cols[CAP];
    __shared__ float srt[CAP];
    __shared__ unsigned char dupf[CAP];
    __shared__ float s_tau, s_thresh;

    int r = blockIdx.x;
    int t = threadIdx.x;
    int m = cnt[r];
    if (m > CAP) m = CAP;

    // zero the LDS row
    float4* rb4 = (float4*)rowbuf;
    float4 z4 = make_float4(0.f, 0.f, 0.f, 0.f);
#pragma unroll
    for (int i = 0; i < 8; ++i) rb4[t + 256 * i] = z4;

    float ab = a[r] + be[0];
    for (int i = t; i < m; i += 256) {
        int c = ecol[r * CAP + i];
        cols[i] = c;
        zs[i] = ab + b[c];
    }
    __syncthreads();

    if (m > 0) {                          // uniform branch
        // phase 1: descending rank (ties by bucket index) + duplicate-col flags
        for (int i = t; i < m; i += 256) {
            float zi = zs[i];
            int ci = cols[i];
            int rank = 0;
            for (int jj = 0; jj < m; ++jj) {
                float zj = zs[jj];
                rank += (zj > zi) || (zj == zi && jj < i);
            }
            bool dup = false;
            for (int jj = 0; jj < i; ++jj)
                if (cols[jj] == ci) { dup = true; break; }
            srt[rank] = zi;
            dupf[i] = dup ? 1 : 0;
        }
        __syncthreads();

        // phase 2: sparsemax support size + tau (serial; m <= 160)
        if (t == 0) {
            float c = 0.f;
            int kmax = 1;
            float csk = srt[0];
            for (int jj = 0; jj < m; ++jj) {
                c += srt[jj];
                if (1.0f + (float)(jj + 1) * srt[jj] > c) { kmax = jj + 1; csk = c; }
            }
            s_tau = (csk - 1.0f) / (float)kmax;
            s_thresh = 0.f;
        }
        __syncthreads();
        float tau = s_tau;

        // phase 3: K-th largest among UNIQUE cols (dups collapse in dense adj)
        for (int i = t; i < m; i += 256) {
            if (dupf[i]) continue;
            float zi = zs[i];
            int rank = 0;
            for (int jj = 0; jj < m; ++jj) {
                if (dupf[jj] || jj == i) continue;
                float zj = zs[jj];
                rank += (zj > zi) || (zj == zi && jj < i);
            }
            if (rank == KTOP - 1) {       // at most one element (strict total order)
                float s = zi - tau;
                s_thresh = s > 0.f ? s : 0.f;
            }
        }
        __syncthreads();
        float thresh = s_thresh;

        // phase 4: scatter kept scores into the LDS row (dup writes identical — benign)
        for (int i = t; i < m; i += 256) {
            float s = zs[i] - tau;
            if (s > 0.f && s >= thresh) rowbuf[cols[i]] = s;
        }
    }
    __syncthreads();

    // stream LDS row -> HBM
    float4* out4 = (float4*)(adj + (size_t)r * N_);
#pragma unroll
    for (int i = 0; i < 8; ++i) out4[t + 256 * i] = rb4[t + 256 * i];
}

extern "C" void kernel_launch(void* const* d_in, const int* in_sizes, int n_in,
                              void* d_out, int out_size, void* d_ws, size_t ws_size,
                              hipStream_t stream) {
    const float* x  = (const float*)d_in[0];
    const int*   ei = (const int*)d_in[1];
    const float* W1 = (const float*)d_in[2];
    const float* b1 = (const float*)d_in[3];
    const float* We = (const float*)d_in[4];
    const float* be = (const float*)d_in[5];

    float* h_out   = (float*)d_out;                 // (N, NHID)
    float* adj_out = h_out + (size_t)N_ * NHID_;    // (N, N)

    float* a    = (float*)d_ws;                     // N
    float* b    = a + N_;                           // N
    int*   cnt  = (int*)(b + N_);                   // N
    int*   ecol = cnt + N_;                         // N*CAP

    hipMemsetAsync(cnt, 0, N_ * sizeof(int), stream);
    k_gemm   <<<N_ / 8, 256, 0, stream>>>(x, W1, b1, h_out);
    k_ab     <<<N_ / 4, 256, 0, stream>>>(h_out, We, a, b);
    k_scatter<<<E_ / 256, 256, 0, stream>>>(ei, cnt, ecol);
    k_rows   <<<N_, 256, 0, stream>>>(cnt, ecol, a, b, be, adj_out);
}

// Round 3
// 386.374 us; speedup vs baseline: 1.1516x; 1.1516x over previous
//
#include <hip/hip_runtime.h>

#define N_    8192
#define FIN_  256
#define NHID_ 128
#define E_    524288
#define KTOP  32
#define CAP   160   // bucket capacity per row; Binomial(E,1/N): mean 64, sigma 8 -> 160 = +12 sigma

// ---------------- fused: h = relu(x @ W1 + b1); a = h.We1; b = h.We2; cnt = 0 --------
// block = 8 rows x 128 cols; thread (row = t>>5, jg = t&31) computes 4 cols.
// Per k-iter: 1 LDS broadcast read (free) + 1 float4 W1 load (L1-served) + 4 FMA.
__global__ __launch_bounds__(256) void k_gemm_ab(const float* __restrict__ x,
                                                 const float* __restrict__ W1,
                                                 const float* __restrict__ b1,
                                                 const float* __restrict__ We,
                                                 float* __restrict__ h,
                                                 float* __restrict__ a,
                                                 float* __restrict__ b,
                                                 int* __restrict__ cnt) {
    __shared__ float xs[8][FIN_];
    int t = threadIdx.x;
    int row0 = blockIdx.x * 8;
    const float4* xg = (const float4*)(x + (size_t)row0 * FIN_);
    float4* xs4 = (float4*)&xs[0][0];
    xs4[t]       = xg[t];          // 8*256 floats = 512 float4, 2 per thread
    xs4[t + 256] = xg[t + 256];
    if (t < 8) cnt[row0 + t] = 0;  // fused cnt zeroing (k_scatter is stream-ordered after)
    __syncthreads();
    int row = t >> 5;
    int jg  = t & 31;
    const float* wp = W1 + jg * 4;
    float4 acc = *(const float4*)(b1 + jg * 4);
    const float* xr = xs[row];
#pragma unroll 8
    for (int k = 0; k < FIN_; ++k) {
        float4 w = *(const float4*)(wp + (size_t)k * NHID_);
        float xv = xr[k];
        acc.x = fmaf(xv, w.x, acc.x);
        acc.y = fmaf(xv, w.y, acc.y);
        acc.z = fmaf(xv, w.z, acc.z);
        acc.w = fmaf(xv, w.w, acc.w);
    }
    acc.x = fmaxf(acc.x, 0.f);
    acc.y = fmaxf(acc.y, 0.f);
    acc.z = fmaxf(acc.z, 0.f);
    acc.w = fmaxf(acc.w, 0.f);
    *(float4*)(h + (size_t)(row0 + row) * NHID_ + jg * 4) = acc;

    // epilogue: per-node scalars from the relu'd registers (32-lane tree per row)
    float4 we1 = *(const float4*)(We + jg * 4);
    float4 we2 = *(const float4*)(We + NHID_ + jg * 4);
    float p = acc.x * we1.x + acc.y * we1.y + acc.z * we1.z + acc.w * we1.w;
    float q = acc.x * we2.x + acc.y * we2.y + acc.z * we2.z + acc.w * we2.w;
#pragma unroll
    for (int o = 16; o > 0; o >>= 1) {
        p += __shfl_down(p, o, 32);
        q += __shfl_down(q, o, 32);
    }
    if (jg == 0) { a[row0 + row] = p; b[row0 + row] = q; }
}

// ---------------- bucket edges by row (fixed-capacity, atomic append) ----------------
__global__ __launch_bounds__(256) void k_scatter(const int* __restrict__ ei,
                                                 int* __restrict__ cnt,
                                                 int* __restrict__ ecol) {
    int e = blockIdx.x * 256 + threadIdx.x;
    int r = ei[e];
    int c = ei[E_ + e];
    int pos = atomicAdd(&cnt[r], 1);
    if (pos < CAP) ecol[r * CAP + pos] = c;
}

// ---------------- per-row sparsemax + topK threshold + dense row write ----------------
// Small LDS (~2.2 KB) -> 8 blocks/CU; the global zero-fill issues immediately and
// overlaps across resident blocks with the rank/tau compute phases.
__global__ __launch_bounds__(256) void k_rows(const int* __restrict__ cnt,
                                              const int* __restrict__ ecol,
                                              const float* __restrict__ a,
                                              const float* __restrict__ b,
                                              const float* __restrict__ be,
                                              float* __restrict__ adj) {
    __shared__ float zs[CAP];
    __shared__ int   cols[CAP];
    __shared__ float srt[CAP];
    __shared__ unsigned char dupf[CAP];
    __shared__ float s_tau, s_thresh;

    int r = blockIdx.x;
    int t = threadIdx.x;
    int m = cnt[r];
    if (m > CAP) m = CAP;

    // zero the dense output row (issues before compute; overlaps across blocks)
    float* row = adj + (size_t)r * N_;
    float4* row4 = (float4*)row;
    float4 z4 = make_float4(0.f, 0.f, 0.f, 0.f);
#pragma unroll
    for (int i = 0; i < 8; ++i) row4[t + 256 * i] = z4;

    // load bucket; z = a[r] + b[c] + be  (b[] is 32 KB, L2-resident gather)
    float ab = a[r] + be[0];
    for (int i = t; i < m; i += 256) {
        int c = ecol[r * CAP + i];
        cols[i] = c;
        zs[i] = ab + b[c];
    }
    __syncthreads();                  // drains vmcnt: zeros committed, LDS visible
    if (m == 0) return;               // uniform branch

    // phase 1: descending rank (ties by bucket index) + duplicate-col flags
    for (int i = t; i < m; i += 256) {
        float zi = zs[i];
        int ci = cols[i];
        int rank = 0;
        for (int jj = 0; jj < m; ++jj) {
            float zj = zs[jj];
            rank += (zj > zi) || (zj == zi && jj < i);
        }
        bool dup = false;
        for (int jj = 0; jj < i; ++jj)
            if (cols[jj] == ci) { dup = true; break; }
        srt[rank] = zi;
        dupf[i] = dup ? 1 : 0;
    }
    __syncthreads();

    // phase 2: sparsemax support size + tau (serial; m <= 160)
    if (t == 0) {
        float c = 0.f;
        int kmax = 1;
        float csk = srt[0];
        for (int jj = 0; jj < m; ++jj) {
            c += srt[jj];
            if (1.0f + (float)(jj + 1) * srt[jj] > c) { kmax = jj + 1; csk = c; }
        }
        s_tau = (csk - 1.0f) / (float)kmax;
        s_thresh = 0.f;
    }
    __syncthreads();
    float tau = s_tau;

    // phase 3: K-th largest among UNIQUE cols (dups collapse in dense adj)
    for (int i = t; i < m; i += 256) {
        if (dupf[i]) continue;
        float zi = zs[i];
        int rank = 0;
        for (int jj = 0; jj < m; ++jj) {
            if (dupf[jj] || jj == i) continue;
            float zj = zs[jj];
            rank += (zj > zi) || (zj == zi && jj < i);
        }
        if (rank == KTOP - 1) {       // at most one element (strict total order)
            float s = zi - tau;
            s_thresh = s > 0.f ? s : 0.f;
        }
    }
    __syncthreads();
    float thresh = s_thresh;

    // phase 4: scatter kept scores over the zeros (dup writes identical — benign)
    for (int i = t; i < m; i += 256) {
        float s = zs[i] - tau;
        if (s > 0.f && s >= thresh) row[cols[i]] = s;
    }
}

extern "C" void kernel_launch(void* const* d_in, const int* in_sizes, int n_in,
                              void* d_out, int out_size, void* d_ws, size_t ws_size,
                              hipStream_t stream) {
    const float* x  = (const float*)d_in[0];
    const int*   ei = (const int*)d_in[1];
    const float* W1 = (const float*)d_in[2];
    const float* b1 = (const float*)d_in[3];
    const float* We = (const float*)d_in[4];
    const float* be = (const float*)d_in[5];

    float* h_out   = (float*)d_out;                 // (N, NHID)
    float* adj_out = h_out + (size_t)N_ * NHID_;    // (N, N)

    float* a    = (float*)d_ws;                     // N
    float* b    = a + N_;                           // N
    int*   cnt  = (int*)(b + N_);                   // N
    int*   ecol = cnt + N_;                         // N*CAP

    k_gemm_ab<<<N_ / 8, 256, 0, stream>>>(x, W1, b1, We, h_out, a, b, cnt);
    k_scatter<<<E_ / 256, 256, 0, stream>>>(ei, cnt, ecol);
    k_rows   <<<N_, 256, 0, stream>>>(cnt, ecol, a, b, be, adj_out);
}